// Round 12
// baseline (6710.042 us; speedup 1.0000x reference)
//
#include <hip/hip_runtime.h>
#include <hip/hip_bf16.h>
#include <math.h>

// R27: fix R26's skew-wrap overlap. R26 failed (absmax 2.5e-3) because
// skew=(rr>>1)&15 WRAPS at rr=32: enc2 (IT=34) row 32 (skew 0) started at
// 1120 < row 31's end 1133 -> rows 32/33 overwrote rows 30/31 in LDS ->
// corrupted activations -> flipped VQ indices. Fix: skew = rr>>1 UNMASKED
// with headroom SKW = IT/2+1; inter-row gap = 1 + ((rr+1)>>1 - (rr>>1)) >= 1
// for all rr -> no overlap at any IT (16/18/34).
// Bank effect (enc2): lane dword addr = 142*loh + 16*lowg; 142%32=14,
// gcd=2 -> 16 even residues (vs 8 unskewed) -> 4 lanes/bank = throughput
// minimum. K=3: stride 39%32=7 odd -> all 32 residues.
// Values and all fma chains bit-identical to R25 (passing, 5.96ms).
// Pipeline: fp64 encoder -> fp32 z, np-exact fp32 VQ, straight-through
// fl(z+fl(q-z)), fp32 decoder, fp32 output writes.

template<typename T> __device__ __forceinline__ T fmaT(T a, T b, T c);
template<> __device__ __forceinline__ double fmaT(double a, double b, double c) { return fma(a, b, c); }
template<> __device__ __forceinline__ float  fmaT(float a, float b, float c)    { return fmaf(a, b, c); }
template<typename T> __device__ __forceinline__ T maxT(T a, T b);
template<> __device__ __forceinline__ double maxT(double a, double b) { return fmax(a, b); }
template<> __device__ __forceinline__ float  maxT(float a, float b)   { return fmaxf(a, b); }

// ---------------------------------------------------------------------------
// LDS-tiled conv. 256 threads = 4 waves; 16x16 output tile x COB couts.
// Single-buffer stage (input tile + weights) -> barrier -> compute.
// Tile layout: row rr starts at rr*RS + SKEW(rr); RS = IT+1 (odd).
// fp64 SKEW(rr) = rr>>1 (doubles, unmasked); fp32 SKEW = 0 (odd RS).
// Weights staged to LDS as TAcc (cvt once); compute reads broadcast.
// Accumulation per output: ci asc, kh asc, kw asc — bit-identical to direct.
// ---------------------------------------------------------------------------
template<typename TIn, typename TAcc, typename TOut, int K, int S, int PAD,
         bool IN_RELU, bool OUT_RELU, bool RES_ADD, int NCI, int COB>
__global__ __launch_bounds__(256, 3)
void conv_tiled(const TIn* __restrict__ in, const float* __restrict__ w,
                const float* __restrict__ bias, const TAcc* __restrict__ res,
                TOut* __restrict__ out,
                int B, int Cin, int Hin, int Win, int Cout, int Hout, int Wout)
{
    constexpr int TILE = 16;
    constexpr int IT   = (TILE - 1) * S + K;   // input tile edge incl. halo
    constexpr int RS   = IT + 1;               // odd row stride
    constexpr bool F64 = (sizeof(TAcc) == 8);
    constexpr int SKW  = F64 ? (IT / 2 + 1) : 0;  // unmasked-skew headroom
    constexpr int ITT  = IT * IT;
    constexpr int CSZ  = IT * RS + SKW;
    constexpr int NEL  = NCI * ITT;
    constexpr int CPW  = COB / 4;
    constexpr int PIX  = 4;
    constexpr int WIN  = (PIX - 1) * S + K;
    constexpr int KK   = K * K;
    constexpr int NWGT = NCI * COB * KK;       // staged weights per round

    __shared__ __align__(16) TAcc tile[NCI * CSZ];
    __shared__ __align__(16) TAcc wlds[NWGT];

    int ntx = Wout / TILE, nty = Hout / TILE, ncb = Cout / COB;
    int g = blockIdx.x;
    int tx = g % ntx; g /= ntx;
    int ty = g % nty; g /= nty;
    int cb = g % ncb;
    int b  = g / ncb;

    int t    = threadIdx.x;
    int wave = t >> 6;
    int lowg = t & 3;
    int loh  = (t >> 2) & 15;
    int co0  = cb * COB + wave * CPW;
    int oh0t = ty * TILE, ow0t = tx * TILE;
    int oh   = oh0t + loh;
    int ow0  = ow0t + lowg * PIX;

    TAcc acc[CPW][PIX];
    #pragma unroll
    for (int c = 0; c < CPW; c++) {
        TAcc bv = (TAcc)bias[co0 + c];
        #pragma unroll
        for (int j = 0; j < PIX; j++) acc[c][j] = bv;
    }

    const int ihb = oh0t * S - PAD;
    const int iwb = ow0t * S - PAD;
    const long inHW = (long)Hin * Win;

    for (int ci0 = 0; ci0 < Cin; ci0 += NCI) {
        __syncthreads();
        for (int e = t; e < NEL; e += 256) {
            int c = e / ITT, rm = e - c * ITT;
            int rr = rm / IT, cc = rm - rr * IT;
            int ih = ihb + rr, iw = iwb + cc;
            TAcc v = (TAcc)0;
            if ((unsigned)ih < (unsigned)Hin && (unsigned)iw < (unsigned)Win)
                v = (TAcc)in[((long)b * Cin + ci0 + c) * inHW + (long)ih * Win + iw];
            if (IN_RELU) v = maxT(v, (TAcc)0);
            int skew = F64 ? (rr >> 1) : 0;
            tile[c * CSZ + rr * RS + skew + cc] = v;
        }
        for (int e = t; e < NWGT; e += 256) {
            int c   = e / (COB * KK);
            int rm  = e - c * (COB * KK);
            int col = rm / KK;
            int tap = rm - col * KK;
            wlds[e] = (TAcc)w[((long)(cb * COB + col) * Cin + (ci0 + c)) * KK + tap];
        }
        __syncthreads();
        #pragma unroll
        for (int c = 0; c < NCI; c++) {
            const TAcc* wp = wlds + (c * COB + wave * CPW) * KK;
            #pragma unroll
            for (int kh = 0; kh < K; kh++) {
                int row = loh * S + kh;
                int skew = F64 ? (row >> 1) : 0;
                const TAcc* rp = tile + c * CSZ + row * RS + skew + lowg * PIX * S;
                TAcc iv[WIN];
                #pragma unroll
                for (int x = 0; x < WIN; x++) iv[x] = rp[x];
                #pragma unroll
                for (int c2 = 0; c2 < CPW; c2++) {
                    #pragma unroll
                    for (int kw = 0; kw < K; kw++) {
                        TAcc wv = wp[c2 * KK + kh * K + kw];
                        #pragma unroll
                        for (int j = 0; j < PIX; j++)
                            acc[c2][j] = fmaT(iv[j * S + kw], wv, acc[c2][j]);
                    }
                }
            }
        }
    }

    long ostride = (long)Hout * Wout;
    long obase = (((long)b * Cout + co0) * Hout + oh) * Wout + ow0;
    #pragma unroll
    for (int c = 0; c < CPW; c++) {
        #pragma unroll
        for (int j = 0; j < PIX; j++) {
            TAcc v = acc[c][j];
            if (RES_ADD) v += res[obase + c * ostride + j];
            if (OUT_RELU) v = maxT(v, (TAcc)0);
            out[obase + c * ostride + j] = (TOut)v;
        }
    }
}

// ---------------------------------------------------------------------------
// LDS-tiled ConvTranspose2d k=4 s=2 p=1, fp32, 4-wave blocks, padded rows.
// Weights staged to LDS per round, read as float4 broadcasts. As R25.
// Per-output fmaf chains replicate the original deconv exactly:
//   even oh: kh=1 (row iy) then kh=3 (row iy-1); odd oh: kh=0 (iy+1), kh=2 (iy)
//   even ow: +i[iw-1]*w[kh][3] then +i[iw]*w[kh][1]
//   odd  ow: +i[iw]*w[kh][2]  then +i[iw+1]*w[kh][0]
// ---------------------------------------------------------------------------
template<int CQ, bool IN_RELU, bool OUT_RELU, bool OUT_TANH, int NCI>
__global__ __launch_bounds__(256, 3)
void deconv_tiled(const float* __restrict__ in, const float* __restrict__ w,
                  const float* __restrict__ bias, float* __restrict__ out,
                  int B, int Cin, int Hin, int Win, int Cout)
{
    constexpr int IT  = 18;
    constexpr int ITT = IT * IT;
    constexpr int RS  = IT + 1;
    constexpr int CSZ = IT * RS;
    constexpr int NEL = NCI * ITT;
    constexpr int NWGT = NCI * CQ * 16;
    int Hout = Hin << 1, Wout = Win << 1;

    __shared__ __align__(16) float tile[NCI * CSZ];
    __shared__ __align__(16) float wlds[NWGT];

    int ntx = Win >> 4, nty = Hin >> 4, ncb = Cout / CQ;
    int g = blockIdx.x;
    int tx = g % ntx; g /= ntx;
    int ty = g % nty; g /= nty;
    int cb = g % ncb;
    int b  = g / ncb;

    int t   = threadIdx.x;
    int tix = t & 15;
    int tiy = t >> 4;
    int ix0 = tx << 4, iy0 = ty << 4;
    int co0 = cb * CQ;

    float acc[CQ][4];
    #pragma unroll
    for (int c = 0; c < CQ; c++) {
        float bv = bias[co0 + c];
        #pragma unroll
        for (int j = 0; j < 4; j++) acc[c][j] = bv;
    }

    const long inHW = (long)Hin * Win;

    for (int ci0 = 0; ci0 < Cin; ci0 += NCI) {
        __syncthreads();
        for (int e = t; e < NEL; e += 256) {
            int c = e / ITT, rm = e - c * ITT;
            int rr = rm / IT, cc = rm - rr * IT;
            int ih = iy0 - 1 + rr, iw = ix0 - 1 + cc;
            float v = 0.f;
            if ((unsigned)ih < (unsigned)Hin && (unsigned)iw < (unsigned)Win)
                v = in[((long)b * Cin + ci0 + c) * inHW + (long)ih * Win + iw];
            if (IN_RELU) v = fmaxf(v, 0.f);
            tile[c * CSZ + rr * RS + cc] = v;
        }
        for (int e = t; e < NWGT; e += 256) {
            int c   = e / (CQ * 16);
            int cc2 = e - c * (CQ * 16);
            int col = cc2 >> 4;
            int tap = cc2 & 15;
            wlds[e] = w[((long)(ci0 + c) * Cout + cb * CQ + col) * 16 + tap];
        }
        __syncthreads();
        #pragma unroll
        for (int c = 0; c < NCI; c++) {
            const float* tp = tile + c * CSZ + tiy * RS + tix;
            float n00 = tp[0],        n01 = tp[1],          n02 = tp[2];
            float n10 = tp[RS],       n11 = tp[RS + 1],     n12 = tp[RS + 2];
            float n20 = tp[2 * RS],   n21 = tp[2 * RS + 1], n22 = tp[2 * RS + 2];
            const float4* wb4 = reinterpret_cast<const float4*>(wlds) + c * CQ * 4;
            #pragma unroll
            for (int cq = 0; cq < CQ; cq++) {
                float4 wA = wb4[cq * 4 + 0];   // w[kh=0][0..3]
                float4 wB = wb4[cq * 4 + 1];   // w[kh=1][0..3]
                float4 wC = wb4[cq * 4 + 2];   // w[kh=2][0..3]
                float4 wD = wb4[cq * 4 + 3];   // w[kh=3][0..3]
                float a0 = acc[cq][0], a1 = acc[cq][1];
                float a2 = acc[cq][2], a3 = acc[cq][3];
                a0 = fmaf(n11, wB.y, fmaf(n10, wB.w, a0));   // wk[5], wk[7]
                a0 = fmaf(n01, wD.y, fmaf(n00, wD.w, a0));   // wk[13], wk[15]
                a1 = fmaf(n12, wB.x, fmaf(n11, wB.z, a1));   // wk[4], wk[6]
                a1 = fmaf(n02, wD.x, fmaf(n01, wD.z, a1));   // wk[12], wk[14]
                a2 = fmaf(n21, wA.y, fmaf(n20, wA.w, a2));   // wk[1], wk[3]
                a2 = fmaf(n11, wC.y, fmaf(n10, wC.w, a2));   // wk[9], wk[11]
                a3 = fmaf(n22, wA.x, fmaf(n21, wA.z, a3));   // wk[0], wk[2]
                a3 = fmaf(n12, wC.x, fmaf(n11, wC.z, a3));   // wk[8], wk[10]
                acc[cq][0] = a0; acc[cq][1] = a1;
                acc[cq][2] = a2; acc[cq][3] = a3;
            }
        }
    }

    int oh0 = (iy0 + tiy) << 1;
    int ow0 = (ix0 + tix) << 1;
    long ostride = (long)Hout * Wout;
    long obase = (((long)b * Cout + co0) * Hout + oh0) * Wout + ow0;
    #pragma unroll
    for (int c = 0; c < CQ; c++) {
        #pragma unroll
        for (int j = 0; j < 4; j++) {
            float v = acc[c][j];
            if (OUT_RELU) v = fmaxf(v, 0.f);
            if (OUT_TANH) v = tanhf(v);
            out[obase + c * ostride + (j >> 1) * (long)Wout + (j & 1)] = v;
        }
    }
}

// numpy pairwise sum-of-squares over 64 fp32 values.
__device__ __forceinline__ float np_sumsq64(const float* v) {
    float r[8];
    #pragma unroll
    for (int j = 0; j < 8; j++) r[j] = __fmul_rn(v[j], v[j]);
    #pragma unroll
    for (int i = 8; i < 64; i += 8) {
        #pragma unroll
        for (int j = 0; j < 8; j++)
            r[j] = __fadd_rn(r[j], __fmul_rn(v[i + j], v[i + j]));
    }
    float s01 = __fadd_rn(r[0], r[1]), s23 = __fadd_rn(r[2], r[3]);
    float s45 = __fadd_rn(r[4], r[5]), s67 = __fadd_rn(r[6], r[7]);
    return __fadd_rn(__fadd_rn(s01, s23), __fadd_rn(s45, s67));
}

__global__ void codenorm_kernel(const float* __restrict__ cb, float* __restrict__ cn)
{
    int k = blockIdx.x * 64 + threadIdx.x;
    if (k >= 512) return;
    float row[64];
    #pragma unroll
    for (int d = 0; d < 64; d++) row[d] = cb[k * 64 + d];
    cn[k] = np_sumsq64(row);
}

// VQ: np-exact fp32 chain; st = fl(z + fl(q-z)). As R22/R24/R25 (passing).
__global__ __launch_bounds__(256)
void vq_kernel(const float* __restrict__ z, const float* __restrict__ cb,
               const float* __restrict__ cn, float* __restrict__ st,
               double* __restrict__ loss_sum, int B)
{
    __shared__ float zt[64][64];
    __shared__ float bd[3][64];
    __shared__ int   bk[3][64];
    int t = threadIdx.x;
    long pg = (long)blockIdx.x * 64;
    int b  = (int)(pg >> 12);
    int p0 = (int)(pg & 4095);
    const float* zb = z + (long)b * 64 * 4096 + p0;
    for (int e = t; e < 64 * 64; e += 256) {
        int d = e >> 6, px = e & 63;
        zt[d][px] = zb[(long)d * 4096 + px];
    }
    __syncthreads();

    int px = t & 63;
    int h  = t >> 6;
    float zr[64];
    #pragma unroll
    for (int d = 0; d < 64; d++) zr[d] = zt[d][px];

    float s1 = np_sumsq64(zr);

    float best = INFINITY;
    int bi = 0;
    int k0 = h << 7;
    for (int k = k0; k < k0 + 128; k += 4) {
        const float* c0 = cb + (k + 0) * 64;
        const float* c1 = cb + (k + 1) * 64;
        const float* c2 = cb + (k + 2) * 64;
        const float* c3 = cb + (k + 3) * 64;
        float m0 = 0.f, m1 = 0.f, m2 = 0.f, m3 = 0.f;
        #pragma unroll
        for (int d = 0; d < 64; d++) {
            float zd = zr[d];
            m0 = fmaf(zd, c0[d], m0);
            m1 = fmaf(zd, c1[d], m1);
            m2 = fmaf(zd, c2[d], m2);
            m3 = fmaf(zd, c3[d], m3);
        }
        float d0 = __fadd_rn(__fsub_rn(s1, __fmul_rn(2.f, m0)), cn[k + 0]);
        float d1 = __fadd_rn(__fsub_rn(s1, __fmul_rn(2.f, m1)), cn[k + 1]);
        float d2 = __fadd_rn(__fsub_rn(s1, __fmul_rn(2.f, m2)), cn[k + 2]);
        float d3 = __fadd_rn(__fsub_rn(s1, __fmul_rn(2.f, m3)), cn[k + 3]);
        if (d0 < best) { best = d0; bi = k + 0; }
        if (d1 < best) { best = d1; bi = k + 1; }
        if (d2 < best) { best = d2; bi = k + 2; }
        if (d3 < best) { best = d3; bi = k + 3; }
    }

    if (h) { bd[h - 1][px] = best; bk[h - 1][px] = bi; }
    __syncthreads();
    if (h == 0) {
        #pragma unroll
        for (int j = 0; j < 3; j++) {
            float dj = bd[j][px];
            if (dj < best) { best = dj; bi = bk[j][px]; }
        }
        const float* cbest = cb + bi * 64;
        float* sp = st + (long)b * 64 * 4096 + (p0 + px);
        double ls = 0.0;
        #pragma unroll
        for (int d = 0; d < 64; d++) {
            float qv = cbest[d];
            float zv = zr[d];
            float diff = __fsub_rn(qv, zv);
            double dd = (double)qv - (double)zv;
            ls += dd * dd;
            sp[(long)d * 4096] = __fadd_rn(zv, diff);
        }
        #pragma unroll
        for (int off = 32; off > 0; off >>= 1) ls += __shfl_down(ls, off, 64);
        if (px == 0) atomicAdd(loss_sum, ls);
    }
}

__global__ void loss_final_kernel(const double* __restrict__ s, float* __restrict__ out)
{
    out[0] = (float)(1.25 * s[0] / 8388608.0);   // fp32 loss store
}

extern "C" void kernel_launch(void* const* d_in, const int* in_sizes, int n_in,
                              void* d_out, int out_size, void* d_ws, size_t ws_size,
                              hipStream_t stream)
{
    const float* x        = (const float*)d_in[0];
    const float* enc_w1   = (const float*)d_in[1];
    const float* enc_b1   = (const float*)d_in[2];
    const float* enc_w2   = (const float*)d_in[3];
    const float* enc_b2   = (const float*)d_in[4];
    const float* enc_w3   = (const float*)d_in[5];
    const float* enc_b3   = (const float*)d_in[6];
    const float* enc_rw1  = (const float*)d_in[7];
    const float* enc_rb1  = (const float*)d_in[8];
    const float* enc_rw2  = (const float*)d_in[9];
    const float* enc_rb2  = (const float*)d_in[10];
    const float* pvq_w    = (const float*)d_in[11];
    const float* pvq_b    = (const float*)d_in[12];
    const float* codebook = (const float*)d_in[13];
    const float* dec_w1   = (const float*)d_in[14];
    const float* dec_b1   = (const float*)d_in[15];
    const float* dec_rw1  = (const float*)d_in[16];
    const float* dec_rb1  = (const float*)d_in[17];
    const float* dec_rw2  = (const float*)d_in[18];
    const float* dec_rb2  = (const float*)d_in[19];
    const float* dt1_w    = (const float*)d_in[20];
    const float* dt1_b    = (const float*)d_in[21];
    const float* dt2_w    = (const float*)d_in[22];
    const float* dt2_b    = (const float*)d_in[23];

    float* out = (float*)d_out;            // fp32 output buffer (ref dtype)
    char* wsb = (char*)d_ws;

    float*  CN = (float*)wsb;              // 512 floats
    double* LS = (double*)(wsb + 4096);    // 1 double
    const size_t SMALLB = 4352;

    // Aliased layout, 12 MB/sample (as R21/R22/R24/R25).
    const size_t perSampleB = 12582912;

    int Bc = 32;
    while (Bc > 1 && SMALLB + perSampleB * Bc + 1024 > ws_size) Bc >>= 1;
    const int nChunks = 32 / Bc;

    char* base  = wsb + SMALLB;
    char* qbase = base + (size_t)Bc * 8388608;
    double* A64 = (double*)base;                              // Bc x 1048576 d
    double* C64 = (double*)base;                              // Bc x 524288 d
    double* T64 = (double*)(base + (size_t)Bc * 4194304);     // Bc x 131072 d
    float*  Z32 = (float*)(base + (size_t)Bc * 5242880);      // Bc x 262144 f
    float*  Qf  = (float*)(base + (size_t)Bc * 6291456);      // Bc x 262144 f
    float*  Ef  = (float*)base;                               // Bc x 1048576 f
    double* B64 = (double*)qbase;                             // Bc x 524288 d
    float*  Df  = (float*)qbase;                              // Bc x 524288 f
    float*  Tf  = (float*)(qbase + (size_t)Bc * 2097152);     // Bc x 131072 f

    hipMemsetAsync(LS, 0, sizeof(double), stream);
    codenorm_kernel<<<8, 64, 0, stream>>>(codebook, CN);

    for (int c = 0; c < nChunks; c++) {
        const float* xc = x + (long)c * Bc * 3 * 65536;
        float* outc = out + (long)c * Bc * 3 * 65536;

        // ---- encoder (fp64 accumulate -> fp32 z) ----
        conv_tiled<float,double,double,4,2,1,false,true,false,3,32>
            <<<Bc*8*8*2, 256, 0, stream>>>(
            xc, enc_w1, enc_b1, nullptr, A64, Bc, 3, 256, 256, 64, 128, 128);
        conv_tiled<double,double,double,4,2,1,false,true,false,2,16>
            <<<Bc*4*4*8, 256, 0, stream>>>(
            A64, enc_w2, enc_b2, nullptr, B64, Bc, 64, 128, 128, 128, 64, 64);
        conv_tiled<double,double,double,3,1,1,false,false,false,4,16>
            <<<Bc*4*4*8, 256, 0, stream>>>(
            B64, enc_w3, enc_b3, nullptr, C64, Bc, 128, 64, 64, 128, 64, 64);
        for (int i = 0; i < 2; i++) {
            conv_tiled<double,double,double,3,1,1,true,false,false,8,8>
                <<<Bc*4*4*4, 256, 0, stream>>>(
                C64, enc_rw1 + (long)i*32*128*9, enc_rb1 + i*32, nullptr, T64,
                Bc, 128, 64, 64, 32, 64, 64);
            conv_tiled<double,double,double,1,1,0,true,false,true,8,16>
                <<<Bc*4*4*8, 256, 0, stream>>>(
                T64, enc_rw2 + (long)i*128*32, enc_rb2 + i*128, C64, C64,
                Bc, 32, 64, 64, 128, 64, 64);
        }
        conv_tiled<double,double,float,1,1,0,true,false,false,8,16>
            <<<Bc*4*4*4, 256, 0, stream>>>(
            C64, pvq_w, pvq_b, nullptr, Z32, Bc, 128, 64, 64, 64, 64, 64);

        // ---- VQ (np-exact fp32) ----
        vq_kernel<<<Bc * 64, 256, 0, stream>>>(Z32, codebook, CN, Qf, LS, Bc);

        // ---- decoder (fp32), fp32 output stores ----
        conv_tiled<float,float,float,3,1,1,false,false,false,8,16>
            <<<Bc*4*4*8, 256, 0, stream>>>(
            Qf, dec_w1, dec_b1, nullptr, Df, Bc, 64, 64, 64, 128, 64, 64);
        for (int i = 0; i < 2; i++) {
            conv_tiled<float,float,float,3,1,1,true,false,false,8,8>
                <<<Bc*4*4*4, 256, 0, stream>>>(
                Df, dec_rw1 + (long)i*32*128*9, dec_rb1 + i*32, nullptr, Tf,
                Bc, 128, 64, 64, 32, 64, 64);
            conv_tiled<float,float,float,1,1,0,true,false,true,16,16>
                <<<Bc*4*4*8, 256, 0, stream>>>(
                Tf, dec_rw2 + (long)i*128*32, dec_rb2 + i*128, Df, Df,
                Bc, 32, 64, 64, 128, 64, 64);
        }
        deconv_tiled<8,true,true,false,8><<<Bc*4*4*8, 256, 0, stream>>>(
            Df, dt1_w, dt1_b, Ef, Bc, 128, 64, 64, 64);
        deconv_tiled<3,false,false,true,8><<<Bc*8*8*1, 256, 0, stream>>>(
            Ef, dt2_w, dt2_b, outc, Bc, 64, 128, 128, 3);
    }

    loss_final_kernel<<<1, 1, 0, stream>>>(LS, out + 6291456);
}

// Round 13
// 5977.990 us; speedup vs baseline: 1.1225x; 1.1225x over previous
//
#include <hip/hip_runtime.h>
#include <hip/hip_bf16.h>
#include <math.h>

// R28 = R25 verbatim (verified 5.96ms, absmax 7.629395e-06). R26 (skew w/
// mask) corrupted LDS via wrap-overlap; R27 (unmasked skew) passed but
// DOUBLED bank conflicts (4.58e7->8.78e7) and regressed to 6.71ms — the
// compute-phase bank model was wrong. LDS-geometry edits are 1-for-4 this
// session; reverting to the verified optimum.
// State: LDS-tiled convs (stage input+weights -> barrier -> compute),
// weights pre-converted to TAcc in LDS (R25), float4 deconv weights + even
// fp32 RS (R24), aliased 12MB/sample workspace -> Bc=16 (R21), COB-halved
// grids (R22), 4-way-split VQ (R22).
// Constraints learned: encoder fp64 sum order is load-bearing (VQ argmin
// discontinuity — R23 MFMA reorder failed); fp64 vector FMA is quarter-rate;
// composite issue floor ~3.2ms, this kernel ~1.86x that.
// Pipeline: fp64 encoder -> fp32 z, np-exact fp32 VQ, straight-through
// fl(z+fl(q-z)), fp32 decoder, fp32 output writes.

template<typename T> __device__ __forceinline__ T fmaT(T a, T b, T c);
template<> __device__ __forceinline__ double fmaT(double a, double b, double c) { return fma(a, b, c); }
template<> __device__ __forceinline__ float  fmaT(float a, float b, float c)    { return fmaf(a, b, c); }
template<typename T> __device__ __forceinline__ T maxT(T a, T b);
template<> __device__ __forceinline__ double maxT(double a, double b) { return fmax(a, b); }
template<> __device__ __forceinline__ float  maxT(float a, float b)   { return fmaxf(a, b); }

// ---------------------------------------------------------------------------
// LDS-tiled conv. 256 threads = 4 waves; 16x16 output tile x COB couts.
// Single-buffer stage (input tile + weights) -> barrier -> compute.
// fp64 tiles: RS=IT+1. fp32 tiles: RS mult-of-4 (vector ds reads).
// Weights staged to LDS as TAcc (cvt once); compute reads broadcast.
// Accumulation per output: ci asc, kh asc, kw asc — bit-identical to direct.
// ---------------------------------------------------------------------------
template<typename TIn, typename TAcc, typename TOut, int K, int S, int PAD,
         bool IN_RELU, bool OUT_RELU, bool RES_ADD, int NCI, int COB>
__global__ __launch_bounds__(256, 3)
void conv_tiled(const TIn* __restrict__ in, const float* __restrict__ w,
                const float* __restrict__ bias, const TAcc* __restrict__ res,
                TOut* __restrict__ out,
                int B, int Cin, int Hin, int Win, int Cout, int Hout, int Wout)
{
    constexpr int TILE = 16;
    constexpr int IT   = (TILE - 1) * S + K;   // input tile edge incl. halo
    constexpr int RS   = (sizeof(TAcc) == 8) ? (IT + 1) : ((IT + 4) & ~3);
    constexpr int ITT  = IT * IT;
    constexpr int CSZ  = IT * RS;
    constexpr int NEL  = NCI * ITT;
    constexpr int CPW  = COB / 4;
    constexpr int PIX  = 4;
    constexpr int WIN  = (PIX - 1) * S + K;
    constexpr int KK   = K * K;
    constexpr int NWGT = NCI * COB * KK;       // staged weights per round

    __shared__ __align__(16) TAcc tile[NCI * CSZ];
    __shared__ __align__(16) TAcc wlds[NWGT];

    int ntx = Wout / TILE, nty = Hout / TILE, ncb = Cout / COB;
    int g = blockIdx.x;
    int tx = g % ntx; g /= ntx;
    int ty = g % nty; g /= nty;
    int cb = g % ncb;
    int b  = g / ncb;

    int t    = threadIdx.x;
    int wave = t >> 6;
    int lowg = t & 3;
    int loh  = (t >> 2) & 15;
    int co0  = cb * COB + wave * CPW;
    int oh0t = ty * TILE, ow0t = tx * TILE;
    int oh   = oh0t + loh;
    int ow0  = ow0t + lowg * PIX;

    TAcc acc[CPW][PIX];
    #pragma unroll
    for (int c = 0; c < CPW; c++) {
        TAcc bv = (TAcc)bias[co0 + c];
        #pragma unroll
        for (int j = 0; j < PIX; j++) acc[c][j] = bv;
    }

    const int ihb = oh0t * S - PAD;
    const int iwb = ow0t * S - PAD;
    const long inHW = (long)Hin * Win;

    for (int ci0 = 0; ci0 < Cin; ci0 += NCI) {
        __syncthreads();
        for (int e = t; e < NEL; e += 256) {
            int c = e / ITT, rm = e - c * ITT;
            int rr = rm / IT, cc = rm - rr * IT;
            int ih = ihb + rr, iw = iwb + cc;
            TAcc v = (TAcc)0;
            if ((unsigned)ih < (unsigned)Hin && (unsigned)iw < (unsigned)Win)
                v = (TAcc)in[((long)b * Cin + ci0 + c) * inHW + (long)ih * Win + iw];
            if (IN_RELU) v = maxT(v, (TAcc)0);
            tile[c * CSZ + rr * RS + cc] = v;
        }
        for (int e = t; e < NWGT; e += 256) {
            int c   = e / (COB * KK);
            int rm  = e - c * (COB * KK);
            int col = rm / KK;
            int tap = rm - col * KK;
            wlds[e] = (TAcc)w[((long)(cb * COB + col) * Cin + (ci0 + c)) * KK + tap];
        }
        __syncthreads();
        #pragma unroll
        for (int c = 0; c < NCI; c++) {
            const TAcc* wp = wlds + (c * COB + wave * CPW) * KK;
            #pragma unroll
            for (int kh = 0; kh < K; kh++) {
                const TAcc* rp = tile + c * CSZ + (loh * S + kh) * RS + lowg * PIX * S;
                TAcc iv[WIN];
                #pragma unroll
                for (int x = 0; x < WIN; x++) iv[x] = rp[x];
                #pragma unroll
                for (int c2 = 0; c2 < CPW; c2++) {
                    #pragma unroll
                    for (int kw = 0; kw < K; kw++) {
                        TAcc wv = wp[c2 * KK + kh * K + kw];
                        #pragma unroll
                        for (int j = 0; j < PIX; j++)
                            acc[c2][j] = fmaT(iv[j * S + kw], wv, acc[c2][j]);
                    }
                }
            }
        }
    }

    long ostride = (long)Hout * Wout;
    long obase = (((long)b * Cout + co0) * Hout + oh) * Wout + ow0;
    #pragma unroll
    for (int c = 0; c < CPW; c++) {
        #pragma unroll
        for (int j = 0; j < PIX; j++) {
            TAcc v = acc[c][j];
            if (RES_ADD) v += res[obase + c * ostride + j];
            if (OUT_RELU) v = maxT(v, (TAcc)0);
            out[obase + c * ostride + j] = (TOut)v;
        }
    }
}

// ---------------------------------------------------------------------------
// LDS-tiled ConvTranspose2d k=4 s=2 p=1, fp32, 4-wave blocks, padded rows.
// Weights staged to LDS per round, read as float4 broadcasts.
// Per-output fmaf chains replicate the original deconv exactly:
//   even oh: kh=1 (row iy) then kh=3 (row iy-1); odd oh: kh=0 (iy+1), kh=2 (iy)
//   even ow: +i[iw-1]*w[kh][3] then +i[iw]*w[kh][1]
//   odd  ow: +i[iw]*w[kh][2]  then +i[iw+1]*w[kh][0]
// ---------------------------------------------------------------------------
template<int CQ, bool IN_RELU, bool OUT_RELU, bool OUT_TANH, int NCI>
__global__ __launch_bounds__(256, 3)
void deconv_tiled(const float* __restrict__ in, const float* __restrict__ w,
                  const float* __restrict__ bias, float* __restrict__ out,
                  int B, int Cin, int Hin, int Win, int Cout)
{
    constexpr int IT  = 18;
    constexpr int ITT = IT * IT;
    constexpr int RS  = IT + 1;
    constexpr int CSZ = IT * RS;
    constexpr int NEL = NCI * ITT;
    constexpr int NWGT = NCI * CQ * 16;
    int Hout = Hin << 1, Wout = Win << 1;

    __shared__ __align__(16) float tile[NCI * CSZ];
    __shared__ __align__(16) float wlds[NWGT];

    int ntx = Win >> 4, nty = Hin >> 4, ncb = Cout / CQ;
    int g = blockIdx.x;
    int tx = g % ntx; g /= ntx;
    int ty = g % nty; g /= nty;
    int cb = g % ncb;
    int b  = g / ncb;

    int t   = threadIdx.x;
    int tix = t & 15;
    int tiy = t >> 4;
    int ix0 = tx << 4, iy0 = ty << 4;
    int co0 = cb * CQ;

    float acc[CQ][4];
    #pragma unroll
    for (int c = 0; c < CQ; c++) {
        float bv = bias[co0 + c];
        #pragma unroll
        for (int j = 0; j < 4; j++) acc[c][j] = bv;
    }

    const long inHW = (long)Hin * Win;

    for (int ci0 = 0; ci0 < Cin; ci0 += NCI) {
        __syncthreads();
        for (int e = t; e < NEL; e += 256) {
            int c = e / ITT, rm = e - c * ITT;
            int rr = rm / IT, cc = rm - rr * IT;
            int ih = iy0 - 1 + rr, iw = ix0 - 1 + cc;
            float v = 0.f;
            if ((unsigned)ih < (unsigned)Hin && (unsigned)iw < (unsigned)Win)
                v = in[((long)b * Cin + ci0 + c) * inHW + (long)ih * Win + iw];
            if (IN_RELU) v = fmaxf(v, 0.f);
            tile[c * CSZ + rr * RS + cc] = v;
        }
        for (int e = t; e < NWGT; e += 256) {
            int c   = e / (CQ * 16);
            int cc2 = e - c * (CQ * 16);
            int col = cc2 >> 4;
            int tap = cc2 & 15;
            wlds[e] = w[((long)(ci0 + c) * Cout + cb * CQ + col) * 16 + tap];
        }
        __syncthreads();
        #pragma unroll
        for (int c = 0; c < NCI; c++) {
            const float* tp = tile + c * CSZ + tiy * RS + tix;
            float n00 = tp[0],        n01 = tp[1],          n02 = tp[2];
            float n10 = tp[RS],       n11 = tp[RS + 1],     n12 = tp[RS + 2];
            float n20 = tp[2 * RS],   n21 = tp[2 * RS + 1], n22 = tp[2 * RS + 2];
            const float4* wb4 = reinterpret_cast<const float4*>(wlds) + c * CQ * 4;
            #pragma unroll
            for (int cq = 0; cq < CQ; cq++) {
                float4 wA = wb4[cq * 4 + 0];   // w[kh=0][0..3]
                float4 wB = wb4[cq * 4 + 1];   // w[kh=1][0..3]
                float4 wC = wb4[cq * 4 + 2];   // w[kh=2][0..3]
                float4 wD = wb4[cq * 4 + 3];   // w[kh=3][0..3]
                float a0 = acc[cq][0], a1 = acc[cq][1];
                float a2 = acc[cq][2], a3 = acc[cq][3];
                a0 = fmaf(n11, wB.y, fmaf(n10, wB.w, a0));   // wk[5], wk[7]
                a0 = fmaf(n01, wD.y, fmaf(n00, wD.w, a0));   // wk[13], wk[15]
                a1 = fmaf(n12, wB.x, fmaf(n11, wB.z, a1));   // wk[4], wk[6]
                a1 = fmaf(n02, wD.x, fmaf(n01, wD.z, a1));   // wk[12], wk[14]
                a2 = fmaf(n21, wA.y, fmaf(n20, wA.w, a2));   // wk[1], wk[3]
                a2 = fmaf(n11, wC.y, fmaf(n10, wC.w, a2));   // wk[9], wk[11]
                a3 = fmaf(n22, wA.x, fmaf(n21, wA.z, a3));   // wk[0], wk[2]
                a3 = fmaf(n12, wC.x, fmaf(n11, wC.z, a3));   // wk[8], wk[10]
                acc[cq][0] = a0; acc[cq][1] = a1;
                acc[cq][2] = a2; acc[cq][3] = a3;
            }
        }
    }

    int oh0 = (iy0 + tiy) << 1;
    int ow0 = (ix0 + tix) << 1;
    long ostride = (long)Hout * Wout;
    long obase = (((long)b * Cout + co0) * Hout + oh0) * Wout + ow0;
    #pragma unroll
    for (int c = 0; c < CQ; c++) {
        #pragma unroll
        for (int j = 0; j < 4; j++) {
            float v = acc[c][j];
            if (OUT_RELU) v = fmaxf(v, 0.f);
            if (OUT_TANH) v = tanhf(v);
            out[obase + c * ostride + (j >> 1) * (long)Wout + (j & 1)] = v;
        }
    }
}

// numpy pairwise sum-of-squares over 64 fp32 values.
__device__ __forceinline__ float np_sumsq64(const float* v) {
    float r[8];
    #pragma unroll
    for (int j = 0; j < 8; j++) r[j] = __fmul_rn(v[j], v[j]);
    #pragma unroll
    for (int i = 8; i < 64; i += 8) {
        #pragma unroll
        for (int j = 0; j < 8; j++)
            r[j] = __fadd_rn(r[j], __fmul_rn(v[i + j], v[i + j]));
    }
    float s01 = __fadd_rn(r[0], r[1]), s23 = __fadd_rn(r[2], r[3]);
    float s45 = __fadd_rn(r[4], r[5]), s67 = __fadd_rn(r[6], r[7]);
    return __fadd_rn(__fadd_rn(s01, s23), __fadd_rn(s45, s67));
}

__global__ void codenorm_kernel(const float* __restrict__ cb, float* __restrict__ cn)
{
    int k = blockIdx.x * 64 + threadIdx.x;
    if (k >= 512) return;
    float row[64];
    #pragma unroll
    for (int d = 0; d < 64; d++) row[d] = cb[k * 64 + d];
    cn[k] = np_sumsq64(row);
}

// VQ: np-exact fp32 chain; st = fl(z + fl(q-z)).
__global__ __launch_bounds__(256)
void vq_kernel(const float* __restrict__ z, const float* __restrict__ cb,
               const float* __restrict__ cn, float* __restrict__ st,
               double* __restrict__ loss_sum, int B)
{
    __shared__ float zt[64][64];
    __shared__ float bd[3][64];
    __shared__ int   bk[3][64];
    int t = threadIdx.x;
    long pg = (long)blockIdx.x * 64;
    int b  = (int)(pg >> 12);
    int p0 = (int)(pg & 4095);
    const float* zb = z + (long)b * 64 * 4096 + p0;
    for (int e = t; e < 64 * 64; e += 256) {
        int d = e >> 6, px = e & 63;
        zt[d][px] = zb[(long)d * 4096 + px];
    }
    __syncthreads();

    int px = t & 63;
    int h  = t >> 6;
    float zr[64];
    #pragma unroll
    for (int d = 0; d < 64; d++) zr[d] = zt[d][px];

    float s1 = np_sumsq64(zr);

    float best = INFINITY;
    int bi = 0;
    int k0 = h << 7;
    for (int k = k0; k < k0 + 128; k += 4) {
        const float* c0 = cb + (k + 0) * 64;
        const float* c1 = cb + (k + 1) * 64;
        const float* c2 = cb + (k + 2) * 64;
        const float* c3 = cb + (k + 3) * 64;
        float m0 = 0.f, m1 = 0.f, m2 = 0.f, m3 = 0.f;
        #pragma unroll
        for (int d = 0; d < 64; d++) {
            float zd = zr[d];
            m0 = fmaf(zd, c0[d], m0);
            m1 = fmaf(zd, c1[d], m1);
            m2 = fmaf(zd, c2[d], m2);
            m3 = fmaf(zd, c3[d], m3);
        }
        float d0 = __fadd_rn(__fsub_rn(s1, __fmul_rn(2.f, m0)), cn[k + 0]);
        float d1 = __fadd_rn(__fsub_rn(s1, __fmul_rn(2.f, m1)), cn[k + 1]);
        float d2 = __fadd_rn(__fsub_rn(s1, __fmul_rn(2.f, m2)), cn[k + 2]);
        float d3 = __fadd_rn(__fsub_rn(s1, __fmul_rn(2.f, m3)), cn[k + 3]);
        if (d0 < best) { best = d0; bi = k + 0; }
        if (d1 < best) { best = d1; bi = k + 1; }
        if (d2 < best) { best = d2; bi = k + 2; }
        if (d3 < best) { best = d3; bi = k + 3; }
    }

    if (h) { bd[h - 1][px] = best; bk[h - 1][px] = bi; }
    __syncthreads();
    if (h == 0) {
        #pragma unroll
        for (int j = 0; j < 3; j++) {
            float dj = bd[j][px];
            if (dj < best) { best = dj; bi = bk[j][px]; }
        }
        const float* cbest = cb + bi * 64;
        float* sp = st + (long)b * 64 * 4096 + (p0 + px);
        double ls = 0.0;
        #pragma unroll
        for (int d = 0; d < 64; d++) {
            float qv = cbest[d];
            float zv = zr[d];
            float diff = __fsub_rn(qv, zv);
            double dd = (double)qv - (double)zv;
            ls += dd * dd;
            sp[(long)d * 4096] = __fadd_rn(zv, diff);
        }
        #pragma unroll
        for (int off = 32; off > 0; off >>= 1) ls += __shfl_down(ls, off, 64);
        if (px == 0) atomicAdd(loss_sum, ls);
    }
}

__global__ void loss_final_kernel(const double* __restrict__ s, float* __restrict__ out)
{
    out[0] = (float)(1.25 * s[0] / 8388608.0);   // fp32 loss store
}

extern "C" void kernel_launch(void* const* d_in, const int* in_sizes, int n_in,
                              void* d_out, int out_size, void* d_ws, size_t ws_size,
                              hipStream_t stream)
{
    const float* x        = (const float*)d_in[0];
    const float* enc_w1   = (const float*)d_in[1];
    const float* enc_b1   = (const float*)d_in[2];
    const float* enc_w2   = (const float*)d_in[3];
    const float* enc_b2   = (const float*)d_in[4];
    const float* enc_w3   = (const float*)d_in[5];
    const float* enc_b3   = (const float*)d_in[6];
    const float* enc_rw1  = (const float*)d_in[7];
    const float* enc_rb1  = (const float*)d_in[8];
    const float* enc_rw2  = (const float*)d_in[9];
    const float* enc_rb2  = (const float*)d_in[10];
    const float* pvq_w    = (const float*)d_in[11];
    const float* pvq_b    = (const float*)d_in[12];
    const float* codebook = (const float*)d_in[13];
    const float* dec_w1   = (const float*)d_in[14];
    const float* dec_b1   = (const float*)d_in[15];
    const float* dec_rw1  = (const float*)d_in[16];
    const float* dec_rb1  = (const float*)d_in[17];
    const float* dec_rw2  = (const float*)d_in[18];
    const float* dec_rb2  = (const float*)d_in[19];
    const float* dt1_w    = (const float*)d_in[20];
    const float* dt1_b    = (const float*)d_in[21];
    const float* dt2_w    = (const float*)d_in[22];
    const float* dt2_b    = (const float*)d_in[23];

    float* out = (float*)d_out;            // fp32 output buffer (ref dtype)
    char* wsb = (char*)d_ws;

    float*  CN = (float*)wsb;              // 512 floats
    double* LS = (double*)(wsb + 4096);    // 1 double
    const size_t SMALLB = 4352;

    // Aliased layout, 12 MB/sample (as R21/R22/R24/R25).
    const size_t perSampleB = 12582912;

    int Bc = 32;
    while (Bc > 1 && SMALLB + perSampleB * Bc + 1024 > ws_size) Bc >>= 1;
    const int nChunks = 32 / Bc;

    char* base  = wsb + SMALLB;
    char* qbase = base + (size_t)Bc * 8388608;
    double* A64 = (double*)base;                              // Bc x 1048576 d
    double* C64 = (double*)base;                              // Bc x 524288 d
    double* T64 = (double*)(base + (size_t)Bc * 4194304);     // Bc x 131072 d
    float*  Z32 = (float*)(base + (size_t)Bc * 5242880);      // Bc x 262144 f
    float*  Qf  = (float*)(base + (size_t)Bc * 6291456);      // Bc x 262144 f
    float*  Ef  = (float*)base;                               // Bc x 1048576 f
    double* B64 = (double*)qbase;                             // Bc x 524288 d
    float*  Df  = (float*)qbase;                              // Bc x 524288 f
    float*  Tf  = (float*)(qbase + (size_t)Bc * 2097152);     // Bc x 131072 f

    hipMemsetAsync(LS, 0, sizeof(double), stream);
    codenorm_kernel<<<8, 64, 0, stream>>>(codebook, CN);

    for (int c = 0; c < nChunks; c++) {
        const float* xc = x + (long)c * Bc * 3 * 65536;
        float* outc = out + (long)c * Bc * 3 * 65536;

        // ---- encoder (fp64 accumulate -> fp32 z) ----
        conv_tiled<float,double,double,4,2,1,false,true,false,3,32>
            <<<Bc*8*8*2, 256, 0, stream>>>(
            xc, enc_w1, enc_b1, nullptr, A64, Bc, 3, 256, 256, 64, 128, 128);
        conv_tiled<double,double,double,4,2,1,false,true,false,2,16>
            <<<Bc*4*4*8, 256, 0, stream>>>(
            A64, enc_w2, enc_b2, nullptr, B64, Bc, 64, 128, 128, 128, 64, 64);
        conv_tiled<double,double,double,3,1,1,false,false,false,4,16>
            <<<Bc*4*4*8, 256, 0, stream>>>(
            B64, enc_w3, enc_b3, nullptr, C64, Bc, 128, 64, 64, 128, 64, 64);
        for (int i = 0; i < 2; i++) {
            conv_tiled<double,double,double,3,1,1,true,false,false,8,8>
                <<<Bc*4*4*4, 256, 0, stream>>>(
                C64, enc_rw1 + (long)i*32*128*9, enc_rb1 + i*32, nullptr, T64,
                Bc, 128, 64, 64, 32, 64, 64);
            conv_tiled<double,double,double,1,1,0,true,false,true,8,16>
                <<<Bc*4*4*8, 256, 0, stream>>>(
                T64, enc_rw2 + (long)i*128*32, enc_rb2 + i*128, C64, C64,
                Bc, 32, 64, 64, 128, 64, 64);
        }
        conv_tiled<double,double,float,1,1,0,true,false,false,8,16>
            <<<Bc*4*4*4, 256, 0, stream>>>(
            C64, pvq_w, pvq_b, nullptr, Z32, Bc, 128, 64, 64, 64, 64, 64);

        // ---- VQ (np-exact fp32) ----
        vq_kernel<<<Bc * 64, 256, 0, stream>>>(Z32, codebook, CN, Qf, LS, Bc);

        // ---- decoder (fp32), fp32 output stores ----
        conv_tiled<float,float,float,3,1,1,false,false,false,8,16>
            <<<Bc*4*4*8, 256, 0, stream>>>(
            Qf, dec_w1, dec_b1, nullptr, Df, Bc, 64, 64, 64, 128, 64, 64);
        for (int i = 0; i < 2; i++) {
            conv_tiled<float,float,float,3,1,1,true,false,false,8,8>
                <<<Bc*4*4*4, 256, 0, stream>>>(
                Df, dec_rw1 + (long)i*32*128*9, dec_rb1 + i*32, nullptr, Tf,
                Bc, 128, 64, 64, 32, 64, 64);
            conv_tiled<float,float,float,1,1,0,true,false,true,16,16>
                <<<Bc*4*4*8, 256, 0, stream>>>(
                Tf, dec_rw2 + (long)i*128*32, dec_rb2 + i*128, Df, Df,
                Bc, 32, 64, 64, 128, 64, 64);
        }
        deconv_tiled<8,true,true,false,8><<<Bc*4*4*8, 256, 0, stream>>>(
            Df, dt1_w, dt1_b, Ef, Bc, 128, 64, 64, 64);
        deconv_tiled<3,false,false,true,8><<<Bc*8*8*1, 256, 0, stream>>>(
            Ef, dt2_w, dt2_b, outc, Bc, 64, 128, 128, 3);
    }

    loss_final_kernel<<<1, 1, 0, stream>>>(LS, out + 6291456);
}